// Round 3
// baseline (1254.698 us; speedup 1.0000x reference)
//
#include <hip/hip_runtime.h>
#include <hip/hip_bf16.h>
#include <math.h>

typedef __hip_bfloat16 bf16;

#define SEQ   2048
#define NPOS  4095          // 2*SEQ-1
#define DIMM  768
#define HEADS 8
#define DK    64
#define HD    512           // HEADS*DK
#define NRELF 192
#define BATCH 2
#define BH    16            // BATCH*HEADS
#define ROWS  4096          // BATCH*SEQ

// ---------------- workspace layout (BYTE offsets) ----------------
// emb fp32 [4095][192]; everything else bf16.
#define OB_EMB   ((size_t)0)
#define OB_RELK  ((size_t)(OB_EMB  + 3145728))   // 4095*192*4 = 3,144,960 -> pad
#define OB_QC    ((size_t)(OB_RELK + 4194304))   // 8*4095*64*2 = 4,193,280 -> pad
#define OB_QP    ((size_t)(OB_QC   + 4194304))   // 16*2048*64*2
#define OB_K     ((size_t)(OB_QP   + 4194304))
#define OB_V     ((size_t)(OB_K    + 4194304))
#define OB_OH    ((size_t)(OB_V    + 4194304))
// total = OB_OH + 4,194,304 = 28.3 MB

__device__ __forceinline__ float b2f(bf16 v) { return __bfloat162float(v); }

// RNE float -> bf16 bits (finite inputs only)
__device__ __forceinline__ unsigned f2bf(float f) {
  unsigned u = __float_as_uint(f);
  return (u + 0x7fffu + ((u >> 16) & 1u)) >> 16;
}
__device__ __forceinline__ unsigned pk2(float a, float b) {
  return f2bf(a) | (f2bf(b) << 16);
}

// decode 4 consecutive bf16 (8B-aligned) into 4 floats
__device__ __forceinline__ void ld4bf(const bf16* p, float f[4]) {
  uint2 u = *reinterpret_cast<const uint2*>(p);
  f[0] = __uint_as_float((u.x & 0xffffu) << 16);
  f[1] = __uint_as_float(u.x & 0xffff0000u);
  f[2] = __uint_as_float((u.y & 0xffffu) << 16);
  f[3] = __uint_as_float(u.y & 0xffff0000u);
}
// decode 8 consecutive bf16 (16B-aligned) into 8 floats
__device__ __forceinline__ void ld8bf(const bf16* p, float f[8]) {
  uint4 u = *reinterpret_cast<const uint4*>(p);
  f[0] = __uint_as_float((u.x & 0xffffu) << 16);
  f[1] = __uint_as_float(u.x & 0xffff0000u);
  f[2] = __uint_as_float((u.y & 0xffffu) << 16);
  f[3] = __uint_as_float(u.y & 0xffff0000u);
  f[4] = __uint_as_float((u.z & 0xffffu) << 16);
  f[5] = __uint_as_float(u.z & 0xffff0000u);
  f[6] = __uint_as_float((u.w & 0xffffu) << 16);
  f[7] = __uint_as_float(u.w & 0xffff0000u);
}

// ---------------- 1. positional embedding (fp32) ----------------
// one 32-lane group per row; lane j = basis j (nb=32). Inf-free.
__global__ void pos_emb_kernel(float* __restrict__ emb) {
  const int row = blockIdx.x * 2 + (threadIdx.x >> 5);
  const int j   = threadIdx.x & 31;
  if (row >= NPOS) return;
  const float dist = (float)(row - (SEQ - 1));
  const float ad   = fabsf(dist);

  // exponential: half_life = 2^(3 + 8*j/31); f = 2^(-ad/hl)
  const float hl    = exp2f(3.0f + 8.0f * (float)j / 31.0f);
  const float f_exp = exp2f(-ad / hl);

  // central mask: width = 2^(j+1)-1
  const float width = exp2f((float)(j + 1)) - 1.0f;
  const float f_cm  = (width > ad) ? 1.0f : 0.0f;

  // gamma pdf: conc = 4(j+1)^2, rate = (j+1)/16
  float prob;
  if (ad > 0.0f) {
    const float c   = 4.0f * (float)((j + 1) * (j + 1));
    const float r   = (float)(j + 1) / 16.0f;
    const float lu  = (c - 1.0f) * logf(ad) - r * ad;
    const float ln_ = lgammaf(c) - c * logf(r);
    prob = expf(lu - ln_) + 1e-8f;
  } else {
    prob = 1e-8f;                 // xlogy path: exp(-inf)=0, +1e-8
  }
  float mx = prob;
  for (int off = 16; off; off >>= 1) mx = fmaxf(mx, __shfl_xor(mx, off, 32));
  const float f_g = prob / mx;

  const float s = (dist > 0.f) ? 1.f : ((dist < 0.f) ? -1.f : 0.f);
  float* e = emb + (size_t)row * NRELF;
  e[j]        = f_exp;
  e[32 + j]   = f_cm;
  e[64 + j]   = f_g;
  e[96 + j]   = s * f_exp;
  e[128 + j]  = s * f_cm;
  e[160 + j]  = s * f_g;
}

// ---------------- 2. rel_k = emb @ Wrel -> bf16 ----------------
// relk[h][p][64]; grid (4, 4095), block 128
__global__ void relk_kernel(const float* __restrict__ emb, const float* __restrict__ Wrel,
                            bf16* __restrict__ relk) {
  __shared__ float erow[NRELF];
  const int p = blockIdx.y;
  const int c = blockIdx.x * 128 + threadIdx.x;
  for (int f = threadIdx.x; f < NRELF; f += 128) erow[f] = emb[(size_t)p * NRELF + f];
  __syncthreads();
  float acc = 0.f;
  for (int f = 0; f < NRELF; f++) acc += erow[f] * Wrel[(size_t)f * HD + c];
  const int h = c >> 6, d = c & 63;
  relk[((size_t)h * NPOS + p) * DK + d] = __float2bfloat16(acc);
}

// ---------------- 3. Q/K/V projection GEMM (fp32 in -> bf16 out) ----------------
// C = x[4096,768] @ W[768,512]; MODE 0: qc/qp (scale+biases), else plain.
template <int MODE>
__global__ __launch_bounds__(256) void proj_gemm(
    const float* __restrict__ A, const float* __restrict__ W,
    const float* __restrict__ cb, const float* __restrict__ pb,
    bf16* __restrict__ outA, bf16* __restrict__ outB) {
  __shared__ __align__(16) float As[16][68];
  __shared__ __align__(16) float Bs[16][68];
  const int t  = threadIdx.x;
  const int tx = t & 15, ty = t >> 4;
  const int m0 = blockIdx.y * 64, n0 = blockIdx.x * 64;
  float acc[4][4] = {};

  for (int k0 = 0; k0 < DIMM; k0 += 16) {
    {
      const int l = t * 4;
      const int m = l >> 4, kk = l & 15;
      const float4 fa = *(const float4*)&A[(size_t)(m0 + m) * DIMM + k0 + kk];
      As[kk + 0][m] = fa.x; As[kk + 1][m] = fa.y;
      As[kk + 2][m] = fa.z; As[kk + 3][m] = fa.w;
      const int kb = l >> 6, nn = l & 63;
      const float4 fb = *(const float4*)&W[(size_t)(k0 + kb) * HD + n0 + nn];
      Bs[kb][nn + 0] = fb.x; Bs[kb][nn + 1] = fb.y;
      Bs[kb][nn + 2] = fb.z; Bs[kb][nn + 3] = fb.w;
    }
    __syncthreads();
#pragma unroll
    for (int kk = 0; kk < 16; kk++) {
      const float4 a = *(const float4*)&As[kk][ty * 4];
      const float4 b = *(const float4*)&Bs[kk][tx * 4];
      acc[0][0] += a.x * b.x; acc[0][1] += a.x * b.y; acc[0][2] += a.x * b.z; acc[0][3] += a.x * b.w;
      acc[1][0] += a.y * b.x; acc[1][1] += a.y * b.y; acc[1][2] += a.y * b.z; acc[1][3] += a.y * b.w;
      acc[2][0] += a.z * b.x; acc[2][1] += a.z * b.y; acc[2][2] += a.z * b.z; acc[2][3] += a.z * b.w;
      acc[3][0] += a.w * b.x; acc[3][1] += a.w * b.y; acc[3][2] += a.w * b.z; acc[3][3] += a.w * b.w;
    }
    __syncthreads();
  }

  const int hh = n0 >> 6;          // head is block-uniform (n0 multiple of 64)
  float4 cbv = make_float4(0, 0, 0, 0), pbv = make_float4(0, 0, 0, 0);
  if (MODE == 0) {
    cbv = *(const float4*)&cb[hh * DK + tx * 4];
    pbv = *(const float4*)&pb[hh * DK + tx * 4];
  }
#pragma unroll
  for (int i = 0; i < 4; i++) {
    const int m = m0 + ty * 4 + i;
    const int b = m >> 11, ns = m & 2047;
    const size_t idx = (((size_t)(b * HEADS + hh) * SEQ) + ns) * DK + tx * 4;
    if (MODE == 0) {
      float v0 = acc[i][0] * 0.125f, v1 = acc[i][1] * 0.125f;
      float v2 = acc[i][2] * 0.125f, v3 = acc[i][3] * 0.125f;
      *(uint2*)&outA[idx] = make_uint2(pk2(v0 + cbv.x, v1 + cbv.y), pk2(v2 + cbv.z, v3 + cbv.w));
      *(uint2*)&outB[idx] = make_uint2(pk2(v0 + pbv.x, v1 + pbv.y), pk2(v2 + pbv.z, v3 + pbv.w));
    } else {
      *(uint2*)&outA[idx] = make_uint2(pk2(acc[i][0], acc[i][1]), pk2(acc[i][2], acc[i][3]));
    }
  }
}

// ---------------- 4. fused attention (online softmax, inf-free) ----------------
// grid (SEQ/32, BH), block 256. thread: ii = t>>3 (q-row), c8 = t&7.
__global__ __launch_bounds__(256, 2) void attn_kernel(
    const bf16* __restrict__ qc_g, const bf16* __restrict__ qp_g,
    const bf16* __restrict__ k_g, const bf16* __restrict__ v_g,
    const bf16* __restrict__ relk_g, bf16* __restrict__ oh) {
  __shared__ __align__(16) float qcs[32][68];
  __shared__ __align__(16) float qps[32][68];
  __shared__ __align__(16) float ks[32][68];
  __shared__ __align__(16) float vs[32][68];
  __shared__ __align__(16) float rels[63][68];
  __shared__ float stile[32][66];

  const int t  = threadIdx.x;
  const int ii = t >> 3;
  const int c8 = t & 7;
  const int bh = blockIdx.y;
  const int b  = bh >> 3, h = bh & 7;
  const int i0 = blockIdx.x * 32;

  {
    const int r = t >> 3, cc = (t & 7) * 8;
    float f[8];
    ld8bf(&qc_g[((size_t)bh * SEQ + i0 + r) * DK + cc], f);
    *(float4*)&qcs[r][cc]     = make_float4(f[0], f[1], f[2], f[3]);
    *(float4*)&qcs[r][cc + 4] = make_float4(f[4], f[5], f[6], f[7]);
    ld8bf(&qp_g[((size_t)bh * SEQ + i0 + r) * DK + cc], f);
    *(float4*)&qps[r][cc]     = make_float4(f[0], f[1], f[2], f[3]);
    *(float4*)&qps[r][cc + 4] = make_float4(f[4], f[5], f[6], f[7]);
  }

  float m_i = -1e30f, l_i = 0.0f;     // finite sentinel: expf(-1e30 - x) == 0, no inf
  float oacc[8] = {0, 0, 0, 0, 0, 0, 0, 0};

  const bf16* kb = k_g + (size_t)bh * SEQ * DK;
  const bf16* vb = v_g + (size_t)bh * SEQ * DK;
  const bf16* rb = relk_g + (size_t)h * NPOS * DK;

  for (int jt = 0; jt < SEQ / 32; jt++) {
    const int j0 = jt * 32;
    __syncthreads();
    {
      const int r = t >> 3, cc = (t & 7) * 8;
      float f[8];
      ld8bf(&kb[(size_t)(j0 + r) * DK + cc], f);
      *(float4*)&ks[r][cc]     = make_float4(f[0], f[1], f[2], f[3]);
      *(float4*)&ks[r][cc + 4] = make_float4(f[4], f[5], f[6], f[7]);
      ld8bf(&vb[(size_t)(j0 + r) * DK + cc], f);
      *(float4*)&vs[r][cc]     = make_float4(f[0], f[1], f[2], f[3]);
      *(float4*)&vs[r][cc + 4] = make_float4(f[4], f[5], f[6], f[7]);
    }
    {
      const int pmin = j0 - i0 + 2016;     // j0 - i0 - 31 + 2047  (in [0,4032])
      const bf16* rsrc = rb + (size_t)pmin * DK;
      for (int l = t; l < 63 * 8; l += 256) {
        const int r = l >> 3, cc = (l & 7) * 8;
        float f[8];
        ld8bf(&rsrc[(size_t)r * DK + cc], f);
        *(float4*)&rels[r][cc]     = make_float4(f[0], f[1], f[2], f[3]);
        *(float4*)&rels[r][cc + 4] = make_float4(f[4], f[5], f[6], f[7]);
      }
    }
    __syncthreads();

    float s[4] = {0, 0, 0, 0};
    const int jbase = c8 * 4;
#pragma unroll 4
    for (int d4 = 0; d4 < 16; d4++) {
      const float4 qc4 = *(const float4*)&qcs[ii][d4 * 4];
      const float4 qp4 = *(const float4*)&qps[ii][d4 * 4];
#pragma unroll
      for (int q = 0; q < 4; q++) {
        const int jj = jbase + q;
        const float4 k4 = *(const float4*)&ks[jj][d4 * 4];
        const float4 r4 = *(const float4*)&rels[jj - ii + 31][d4 * 4];
        s[q] += qc4.x * k4.x + qc4.y * k4.y + qc4.z * k4.z + qc4.w * k4.w
              + qp4.x * r4.x + qp4.y * r4.y + qp4.z * r4.z + qp4.w * r4.w;
      }
    }

    // online softmax across the 8 lanes of this row (consecutive, 8-aligned)
    float mloc = fmaxf(fmaxf(s[0], s[1]), fmaxf(s[2], s[3]));
    mloc = fmaxf(mloc, __shfl_xor(mloc, 4, 8));
    mloc = fmaxf(mloc, __shfl_xor(mloc, 2, 8));
    mloc = fmaxf(mloc, __shfl_xor(mloc, 1, 8));
    const float m_new = fmaxf(m_i, mloc);
    const float alpha = expf(m_i - m_new);
    float lloc = 0.f;
#pragma unroll
    for (int q = 0; q < 4; q++) {
      const float p = expf(s[q] - m_new);
      stile[ii][jbase + q] = p;
      lloc += p;
    }
    lloc += __shfl_xor(lloc, 4, 8);
    lloc += __shfl_xor(lloc, 2, 8);
    lloc += __shfl_xor(lloc, 1, 8);
    l_i = l_i * alpha + lloc;
    m_i = m_new;
#pragma unroll
    for (int d = 0; d < 8; d++) oacc[d] *= alpha;
    __syncthreads();

#pragma unroll 8
    for (int jj = 0; jj < 32; jj++) {
      const float p = stile[ii][jj];
      const float4 va  = *(const float4*)&vs[jj][c8 * 8];
      const float4 vb4 = *(const float4*)&vs[jj][c8 * 8 + 4];
      oacc[0] += p * va.x;  oacc[1] += p * va.y;  oacc[2] += p * va.z;  oacc[3] += p * va.w;
      oacc[4] += p * vb4.x; oacc[5] += p * vb4.y; oacc[6] += p * vb4.z; oacc[7] += p * vb4.w;
    }
  }

  const float inv = 1.0f / l_i;
  bf16* dst = oh + ((size_t)(b * SEQ + i0 + ii) * HD) + h * DK + c8 * 8;
  uint4 pkt;
  pkt.x = pk2(oacc[0] * inv, oacc[1] * inv);
  pkt.y = pk2(oacc[2] * inv, oacc[3] * inv);
  pkt.z = pk2(oacc[4] * inv, oacc[5] * inv);
  pkt.w = pk2(oacc[6] * inv, oacc[7] * inv);
  *(uint4*)dst = pkt;
}

// ---------------- 5. output projection (bf16 A, fp32 W/bias -> fp32 out) ----------------
// out = oh[4096,512](bf16) @ Wout[512,768] + b_out
__global__ __launch_bounds__(256) void out_gemm(
    const bf16* __restrict__ A, const float* __restrict__ W,
    const float* __restrict__ bias, float* __restrict__ out) {
  __shared__ __align__(16) float As[16][68];
  __shared__ __align__(16) float Bs[16][68];
  const int t  = threadIdx.x;
  const int tx = t & 15, ty = t >> 4;
  const int m0 = blockIdx.y * 64, n0 = blockIdx.x * 64;
  float acc[4][4] = {};

  for (int k0 = 0; k0 < HD; k0 += 16) {
    {
      const int l = t * 4;
      const int m = l >> 4, kk = l & 15;
      float fa[4];
      ld4bf(&A[(size_t)(m0 + m) * HD + k0 + kk], fa);
      As[kk + 0][m] = fa[0]; As[kk + 1][m] = fa[1];
      As[kk + 2][m] = fa[2]; As[kk + 3][m] = fa[3];
      const int kbd = l >> 6, nn = l & 63;
      const float4 fb = *(const float4*)&W[(size_t)(k0 + kbd) * DIMM + n0 + nn];
      Bs[kbd][nn + 0] = fb.x; Bs[kbd][nn + 1] = fb.y;
      Bs[kbd][nn + 2] = fb.z; Bs[kbd][nn + 3] = fb.w;
    }
    __syncthreads();
#pragma unroll
    for (int kk = 0; kk < 16; kk++) {
      const float4 a = *(const float4*)&As[kk][ty * 4];
      const float4 b = *(const float4*)&Bs[kk][tx * 4];
      acc[0][0] += a.x * b.x; acc[0][1] += a.x * b.y; acc[0][2] += a.x * b.z; acc[0][3] += a.x * b.w;
      acc[1][0] += a.y * b.x; acc[1][1] += a.y * b.y; acc[1][2] += a.y * b.z; acc[1][3] += a.y * b.w;
      acc[2][0] += a.z * b.x; acc[2][1] += a.z * b.y; acc[2][2] += a.z * b.z; acc[2][3] += a.z * b.w;
      acc[3][0] += a.w * b.x; acc[3][1] += a.w * b.y; acc[3][2] += a.w * b.z; acc[3][3] += a.w * b.w;
    }
    __syncthreads();
  }

  const float4 bv = *(const float4*)&bias[n0 + tx * 4];
#pragma unroll
  for (int i = 0; i < 4; i++) {
    const int m = m0 + ty * 4 + i;
    *(float4*)&out[(size_t)m * DIMM + n0 + tx * 4] =
        make_float4(acc[i][0] + bv.x, acc[i][1] + bv.y, acc[i][2] + bv.z, acc[i][3] + bv.w);
  }
}

// ---------------- launch ----------------
extern "C" void kernel_launch(void* const* d_in, const int* in_sizes, int n_in,
                              void* d_out, int out_size, void* d_ws, size_t ws_size,
                              hipStream_t stream) {
  (void)in_sizes; (void)n_in; (void)out_size; (void)ws_size;
  const float* x    = (const float*)d_in[0];
  const float* Wq   = (const float*)d_in[1];
  const float* Wk   = (const float*)d_in[2];
  const float* Wv   = (const float*)d_in[3];
  const float* Wrel = (const float*)d_in[4];
  const float* Wout = (const float*)d_in[5];
  const float* bout = (const float*)d_in[6];
  const float* cb   = (const float*)d_in[7];
  const float* pb   = (const float*)d_in[8];
  float* out = (float*)d_out;

  char* ws = (char*)d_ws;
  float* emb = (float*)(ws + OB_EMB);
  bf16* relk = (bf16*)(ws + OB_RELK);
  bf16* qc   = (bf16*)(ws + OB_QC);
  bf16* qp   = (bf16*)(ws + OB_QP);
  bf16* kk   = (bf16*)(ws + OB_K);
  bf16* vv   = (bf16*)(ws + OB_V);
  bf16* oh   = (bf16*)(ws + OB_OH);

  hipLaunchKernelGGL(pos_emb_kernel, dim3(2048), dim3(64), 0, stream, emb);
  hipLaunchKernelGGL(relk_kernel, dim3(4, NPOS), dim3(128), 0, stream, emb, Wrel, relk);
  hipLaunchKernelGGL((proj_gemm<0>), dim3(8, 64), dim3(256), 0, stream, x, Wq, cb, pb, qc, qp);
  hipLaunchKernelGGL((proj_gemm<1>), dim3(8, 64), dim3(256), 0, stream, x, Wk, cb, pb, kk, (bf16*)nullptr);
  hipLaunchKernelGGL((proj_gemm<2>), dim3(8, 64), dim3(256), 0, stream, x, Wv, cb, pb, vv, (bf16*)nullptr);
  hipLaunchKernelGGL(attn_kernel, dim3(SEQ / 32, BH), dim3(256), 0, stream, qc, qp, kk, vv, relk, oh);
  hipLaunchKernelGGL(out_gemm, dim3(DIMM / 64, ROWS / 64), dim3(256), 0, stream, oh, Wout, bout, out);
}

// Round 4
// 458.302 us; speedup vs baseline: 2.7377x; 2.7377x over previous
//
#include <hip/hip_runtime.h>
#include <hip/hip_bf16.h>
#include <math.h>

typedef __hip_bfloat16 bf16;
typedef __attribute__((ext_vector_type(8))) short short8;  // 8 bf16 = 4 VGPRs
typedef __attribute__((ext_vector_type(4))) float f32x4;

#define SEQ   2048
#define NPOS  4095          // 2*SEQ-1
#define DIMM  768
#define HEADS 8
#define DK    64
#define HD    512           // HEADS*DK
#define NRELF 192
#define BATCH 2
#define BH    16            // BATCH*HEADS
#define ROWS  4096          // BATCH*SEQ

// ---------------- workspace layout (BYTE offsets) ----------------
#define OB_EMB   ((size_t)0)
#define OB_RELK  ((size_t)(OB_EMB  + 3145728))
#define OB_QC    ((size_t)(OB_RELK + 4194304))
#define OB_QP    ((size_t)(OB_QC   + 4194304))
#define OB_K     ((size_t)(OB_QP   + 4194304))
#define OB_V     ((size_t)(OB_K    + 4194304))
#define OB_OH    ((size_t)(OB_V    + 4194304))
// total = OB_OH + 4,194,304 = 28.3 MB

__device__ __forceinline__ float b2f(bf16 v) { return __bfloat162float(v); }

// RNE float -> bf16 bits (finite inputs only)
__device__ __forceinline__ unsigned f2bf(float f) {
  unsigned u = __float_as_uint(f);
  return (u + 0x7fffu + ((u >> 16) & 1u)) >> 16;
}
__device__ __forceinline__ unsigned pk2(float a, float b) {
  return f2bf(a) | (f2bf(b) << 16);
}

// decode 4 consecutive bf16 (8B-aligned) into 4 floats
__device__ __forceinline__ void ld4bf(const bf16* p, float f[4]) {
  uint2 u = *reinterpret_cast<const uint2*>(p);
  f[0] = __uint_as_float((u.x & 0xffffu) << 16);
  f[1] = __uint_as_float(u.x & 0xffff0000u);
  f[2] = __uint_as_float((u.y & 0xffffu) << 16);
  f[3] = __uint_as_float(u.y & 0xffff0000u);
}

// ---------------- 1. positional embedding (fp32) ----------------
__global__ void pos_emb_kernel(float* __restrict__ emb) {
  const int row = blockIdx.x * 2 + (threadIdx.x >> 5);
  const int j   = threadIdx.x & 31;
  if (row >= NPOS) return;
  const float dist = (float)(row - (SEQ - 1));
  const float ad   = fabsf(dist);

  const float hl    = exp2f(3.0f + 8.0f * (float)j / 31.0f);
  const float f_exp = exp2f(-ad / hl);

  const float width = exp2f((float)(j + 1)) - 1.0f;
  const float f_cm  = (width > ad) ? 1.0f : 0.0f;

  float prob;
  if (ad > 0.0f) {
    const float c   = 4.0f * (float)((j + 1) * (j + 1));
    const float r   = (float)(j + 1) / 16.0f;
    const float lu  = (c - 1.0f) * logf(ad) - r * ad;
    const float ln_ = lgammaf(c) - c * logf(r);
    prob = expf(lu - ln_) + 1e-8f;
  } else {
    prob = 1e-8f;
  }
  float mx = prob;
  for (int off = 16; off; off >>= 1) mx = fmaxf(mx, __shfl_xor(mx, off, 32));
  const float f_g = prob / mx;

  const float s = (dist > 0.f) ? 1.f : ((dist < 0.f) ? -1.f : 0.f);
  float* e = emb + (size_t)row * NRELF;
  e[j]        = f_exp;
  e[32 + j]   = f_cm;
  e[64 + j]   = f_g;
  e[96 + j]   = s * f_exp;
  e[128 + j]  = s * f_cm;
  e[160 + j]  = s * f_g;
}

// ---------------- 2. rel_k = emb @ Wrel -> bf16 ----------------
__global__ void relk_kernel(const float* __restrict__ emb, const float* __restrict__ Wrel,
                            bf16* __restrict__ relk) {
  __shared__ float erow[NRELF];
  const int p = blockIdx.y;
  const int c = blockIdx.x * 128 + threadIdx.x;
  for (int f = threadIdx.x; f < NRELF; f += 128) erow[f] = emb[(size_t)p * NRELF + f];
  __syncthreads();
  float acc = 0.f;
  for (int f = 0; f < NRELF; f++) acc += erow[f] * Wrel[(size_t)f * HD + c];
  const int h = c >> 6, d = c & 63;
  relk[((size_t)h * NPOS + p) * DK + d] = __float2bfloat16(acc);
}

// ---------------- 3. Q/K/V projection GEMM (fp32 in -> bf16 out) ----------------
template <int MODE>
__global__ __launch_bounds__(256) void proj_gemm(
    const float* __restrict__ A, const float* __restrict__ W,
    const float* __restrict__ cb, const float* __restrict__ pb,
    bf16* __restrict__ outA, bf16* __restrict__ outB) {
  __shared__ __align__(16) float As[16][68];
  __shared__ __align__(16) float Bs[16][68];
  const int t  = threadIdx.x;
  const int tx = t & 15, ty = t >> 4;
  const int m0 = blockIdx.y * 64, n0 = blockIdx.x * 64;
  float acc[4][4] = {};

  for (int k0 = 0; k0 < DIMM; k0 += 16) {
    {
      const int l = t * 4;
      const int m = l >> 4, kk = l & 15;
      const float4 fa = *(const float4*)&A[(size_t)(m0 + m) * DIMM + k0 + kk];
      As[kk + 0][m] = fa.x; As[kk + 1][m] = fa.y;
      As[kk + 2][m] = fa.z; As[kk + 3][m] = fa.w;
      const int kb = l >> 6, nn = l & 63;
      const float4 fb = *(const float4*)&W[(size_t)(k0 + kb) * HD + n0 + nn];
      Bs[kb][nn + 0] = fb.x; Bs[kb][nn + 1] = fb.y;
      Bs[kb][nn + 2] = fb.z; Bs[kb][nn + 3] = fb.w;
    }
    __syncthreads();
#pragma unroll
    for (int kk = 0; kk < 16; kk++) {
      const float4 a = *(const float4*)&As[kk][ty * 4];
      const float4 b = *(const float4*)&Bs[kk][tx * 4];
      acc[0][0] += a.x * b.x; acc[0][1] += a.x * b.y; acc[0][2] += a.x * b.z; acc[0][3] += a.x * b.w;
      acc[1][0] += a.y * b.x; acc[1][1] += a.y * b.y; acc[1][2] += a.y * b.z; acc[1][3] += a.y * b.w;
      acc[2][0] += a.z * b.x; acc[2][1] += a.z * b.y; acc[2][2] += a.z * b.z; acc[2][3] += a.z * b.w;
      acc[3][0] += a.w * b.x; acc[3][1] += a.w * b.y; acc[3][2] += a.w * b.z; acc[3][3] += a.w * b.w;
    }
    __syncthreads();
  }

  const int hh = n0 >> 6;
  float4 cbv = make_float4(0, 0, 0, 0), pbv = make_float4(0, 0, 0, 0);
  if (MODE == 0) {
    cbv = *(const float4*)&cb[hh * DK + tx * 4];
    pbv = *(const float4*)&pb[hh * DK + tx * 4];
  }
#pragma unroll
  for (int i = 0; i < 4; i++) {
    const int m = m0 + ty * 4 + i;
    const int b = m >> 11, ns = m & 2047;
    const size_t idx = (((size_t)(b * HEADS + hh) * SEQ) + ns) * DK + tx * 4;
    if (MODE == 0) {
      float v0 = acc[i][0] * 0.125f, v1 = acc[i][1] * 0.125f;
      float v2 = acc[i][2] * 0.125f, v3 = acc[i][3] * 0.125f;
      *(uint2*)&outA[idx] = make_uint2(pk2(v0 + cbv.x, v1 + cbv.y), pk2(v2 + cbv.z, v3 + cbv.w));
      *(uint2*)&outB[idx] = make_uint2(pk2(v0 + pbv.x, v1 + pbv.y), pk2(v2 + pbv.z, v3 + pbv.w));
    } else {
      *(uint2*)&outA[idx] = make_uint2(pk2(acc[i][0], acc[i][1]), pk2(acc[i][2], acc[i][3]));
    }
  }
}

// ---------------- 4. MFMA fused attention ----------------
// grid (SEQ/64, BH), block 256 = 4 waves; wave w owns q-rows [i0+16w, i0+16w+16).
// MFMA 16x16x32 bf16. C/D: col=lane&15, row=(lane>>4)*4+reg. A: A[m=lane&15][k=quad*8+j].
// B: B[k=quad*8+j][n=lane&15].
__global__ __launch_bounds__(256, 2) void attn_mfma(
    const short* __restrict__ qc, const short* __restrict__ qp,
    const short* __restrict__ kg, const short* __restrict__ vg,
    const short* __restrict__ relk, bf16* __restrict__ oh) {
  // pads: 72 shorts (144 B) / 84 floats keep b128 16B-aligned and <=2-way banked
  __shared__ short Rel_lds[128][72];     // block's rel window (128 rows exactly)
  __shared__ short Vt[64][72];           // V transposed: Vt[d][j]
  __shared__ short Pw[4][16][72];        // per-wave P in A-layout feed
  __shared__ float Rw[4][16][84];        // per-wave rel logits (pre-shift)

  const int t    = threadIdx.x;
  const int lane = t & 63;
  const int w    = t >> 6;
  const int quad = lane >> 4;
  const int l15  = lane & 15;
  const int bh   = blockIdx.y;
  const int b    = bh >> 3, h = bh & 7;
  const int i0   = blockIdx.x * 64;

  // Q fragments (A-operand), loaded once: rows i0+16w+l15, k split in two 32-chunks
  short8 qcA[2], qpA[2];
  {
    const size_t qrow = ((size_t)bh * SEQ + i0 + w * 16 + l15) * DK + quad * 8;
    qcA[0] = *(const short8*)(qc + qrow);
    qcA[1] = *(const short8*)(qc + qrow + 32);
    qpA[0] = *(const short8*)(qp + qrow);
    qpA[1] = *(const short8*)(qp + qrow + 32);
  }

  f32x4 oacc[4];
#pragma unroll
  for (int dt = 0; dt < 4; dt++) oacc[dt] = (f32x4){0.f, 0.f, 0.f, 0.f};
  float m_i[4] = {-1e30f, -1e30f, -1e30f, -1e30f};
  float l_i[4] = {0.f, 0.f, 0.f, 0.f};

  // staging assignments
  const int vjj = t & 63, vdb = (t >> 6) * 16;     // V: row j=vjj, d chunk vdb..vdb+15
  const int rr  = t >> 1, rcc = (t & 1) * 32;      // rel: row rr, col chunk rcc..rcc+31
  const int rbase = 48 - 16 * w;                   // wave's window offset in Rel_lds

  for (int jt = 0; jt < SEQ / 64; jt++) {
    const int j0 = jt * 64;
    __syncthreads();     // previous iteration done with Vt
    // ---- stage V transposed ----
    {
      const short* src = vg + ((size_t)bh * SEQ + j0 + vjj) * DK + vdb;
      uint4 a = *(const uint4*)src;
      uint4 c = *(const uint4*)(src + 8);
      const short* pa = (const short*)&a;
      const short* pc = (const short*)&c;
#pragma unroll
      for (int e = 0; e < 8; e++) {
        Vt[vdb + e][vjj]     = pa[e];
        Vt[vdb + 8 + e][vjj] = pc[e];
      }
    }
    // ---- stage rel rows: p in [j0-i0+1984, j0-i0+2111] ----
    {
      const short* src = relk + ((size_t)h * NPOS + (j0 - i0 + 1984) + rr) * DK + rcc;
      *(uint4*)&Rel_lds[rr][rcc]      = *(const uint4*)(src);
      *(uint4*)&Rel_lds[rr][rcc + 8]  = *(const uint4*)(src + 8);
      *(uint4*)&Rel_lds[rr][rcc + 16] = *(const uint4*)(src + 16);
      *(uint4*)&Rel_lds[rr][rcc + 24] = *(const uint4*)(src + 24);
    }
    __syncthreads();

    // ---- content: S[r][c] = qc_row . k_col, K B-frags direct from global ----
    f32x4 sacc[4];
#pragma unroll
    for (int nt = 0; nt < 4; nt++) {
      const short* kr = kg + ((size_t)bh * SEQ + j0 + nt * 16 + l15) * DK + quad * 8;
      short8 b0 = *(const short8*)kr;
      short8 b1 = *(const short8*)(kr + 32);
      f32x4 acc = (f32x4){0.f, 0.f, 0.f, 0.f};
      acc = __builtin_amdgcn_mfma_f32_16x16x32_bf16(qcA[0], b0, acc, 0, 0, 0);
      acc = __builtin_amdgcn_mfma_f32_16x16x32_bf16(qcA[1], b1, acc, 0, 0, 0);
      sacc[nt] = acc;
    }
    // ---- rel logits R[r][u] = qp_row . rel_k[pw0+u], u in [0,80) ----
#pragma unroll
    for (int ut = 0; ut < 5; ut++) {
      const short* rl = &Rel_lds[rbase + ut * 16 + l15][quad * 8];
      short8 b0 = *(const short8*)rl;
      short8 b1 = *(const short8*)(rl + 32);
      f32x4 acc = (f32x4){0.f, 0.f, 0.f, 0.f};
      acc = __builtin_amdgcn_mfma_f32_16x16x32_bf16(qpA[0], b0, acc, 0, 0, 0);
      acc = __builtin_amdgcn_mfma_f32_16x16x32_bf16(qpA[1], b1, acc, 0, 0, 0);
#pragma unroll
      for (int g = 0; g < 4; g++) Rw[w][quad * 4 + g][ut * 16 + l15] = acc[g];
    }
    // ---- gather rel-shift: S[r][c] += R[r][c - r + 15] (wave-private, no barrier) ----
#pragma unroll
    for (int nt = 0; nt < 4; nt++) {
#pragma unroll
      for (int g = 0; g < 4; g++) {
        const int r = quad * 4 + g;
        sacc[nt][g] += Rw[w][r][nt * 16 + l15 - r + 15];
      }
    }

    // ---- online softmax (rows live in quads; width-16 shuffles) ----
    float m_new[4], alpha[4], lrow[4];
#pragma unroll
    for (int g = 0; g < 4; g++) {
      float mm = fmaxf(fmaxf(sacc[0][g], sacc[1][g]), fmaxf(sacc[2][g], sacc[3][g]));
      mm = fmaxf(mm, __shfl_xor(mm, 1, 16));
      mm = fmaxf(mm, __shfl_xor(mm, 2, 16));
      mm = fmaxf(mm, __shfl_xor(mm, 4, 16));
      mm = fmaxf(mm, __shfl_xor(mm, 8, 16));
      m_new[g] = fmaxf(m_i[g], mm);
      alpha[g] = expf(m_i[g] - m_new[g]);
      m_i[g]   = m_new[g];
      lrow[g]  = 0.f;
    }
#pragma unroll
    for (int nt = 0; nt < 4; nt++) {
#pragma unroll
      for (int g = 0; g < 4; g++) {
        const float p = expf(sacc[nt][g] - m_new[g]);
        lrow[g] += p;
        Pw[w][quad * 4 + g][nt * 16 + l15] = (short)f2bf(p);
      }
    }
#pragma unroll
    for (int g = 0; g < 4; g++) {
      float ls = lrow[g];
      ls += __shfl_xor(ls, 1, 16);
      ls += __shfl_xor(ls, 2, 16);
      ls += __shfl_xor(ls, 4, 16);
      ls += __shfl_xor(ls, 8, 16);
      l_i[g] = l_i[g] * alpha[g] + ls;
    }
#pragma unroll
    for (int dt = 0; dt < 4; dt++) {
#pragma unroll
      for (int g = 0; g < 4; g++) oacc[dt][g] *= alpha[g];
    }

    // ---- PV: O += P(16x64) . V(64x64); P from Pw (A-layout), V from Vt (B-layout) ----
#pragma unroll
    for (int ks = 0; ks < 2; ks++) {
      short8 pA = *(const short8*)&Pw[w][l15][ks * 32 + quad * 8];
#pragma unroll
      for (int dt = 0; dt < 4; dt++) {
        short8 vB = *(const short8*)&Vt[dt * 16 + l15][ks * 32 + quad * 8];
        oacc[dt] = __builtin_amdgcn_mfma_f32_16x16x32_bf16(pA, vB, oacc[dt], 0, 0, 0);
      }
    }
  }

  // ---- epilogue: normalize, store bf16 ----
#pragma unroll
  for (int g = 0; g < 4; g++) {
    const float inv = 1.0f / l_i[g];
    const int irow = i0 + w * 16 + quad * 4 + g;
    bf16* dst = oh + ((size_t)(b * SEQ) + irow) * HD + h * DK + l15;
#pragma unroll
    for (int dt = 0; dt < 4; dt++)
      dst[dt * 16] = __float2bfloat16(oacc[dt][g] * inv);
  }
}

// ---------------- 5. output projection (bf16 A, fp32 W/bias -> fp32 out) ----------------
__global__ __launch_bounds__(256) void out_gemm(
    const bf16* __restrict__ A, const float* __restrict__ W,
    const float* __restrict__ bias, float* __restrict__ out) {
  __shared__ __align__(16) float As[16][68];
  __shared__ __align__(16) float Bs[16][68];
  const int t  = threadIdx.x;
  const int tx = t & 15, ty = t >> 4;
  const int m0 = blockIdx.y * 64, n0 = blockIdx.x * 64;
  float acc[4][4] = {};

  for (int k0 = 0; k0 < HD; k0 += 16) {
    {
      const int l = t * 4;
      const int m = l >> 4, kk = l & 15;
      float fa[4];
      ld4bf(&A[(size_t)(m0 + m) * HD + k0 + kk], fa);
      As[kk + 0][m] = fa[0]; As[kk + 1][m] = fa[1];
      As[kk + 2][m] = fa[2]; As[kk + 3][m] = fa[3];
      const int kbd = l >> 6, nn = l & 63;
      const float4 fb = *(const float4*)&W[(size_t)(k0 + kbd) * DIMM + n0 + nn];
      Bs[kbd][nn + 0] = fb.x; Bs[kbd][nn + 1] = fb.y;
      Bs[kbd][nn + 2] = fb.z; Bs[kbd][nn + 3] = fb.w;
    }
    __syncthreads();
#pragma unroll
    for (int kk = 0; kk < 16; kk++) {
      const float4 a = *(const float4*)&As[kk][ty * 4];
      const float4 b = *(const float4*)&Bs[kk][tx * 4];
      acc[0][0] += a.x * b.x; acc[0][1] += a.x * b.y; acc[0][2] += a.x * b.z; acc[0][3] += a.x * b.w;
      acc[1][0] += a.y * b.x; acc[1][1] += a.y * b.y; acc[1][2] += a.y * b.z; acc[1][3] += a.y * b.w;
      acc[2][0] += a.z * b.x; acc[2][1] += a.z * b.y; acc[2][2] += a.z * b.z; acc[2][3] += a.z * b.w;
      acc[3][0] += a.w * b.x; acc[3][1] += a.w * b.y; acc[3][2] += a.w * b.z; acc[3][3] += a.w * b.w;
    }
    __syncthreads();
  }

  const float4 bv = *(const float4*)&bias[n0 + tx * 4];
#pragma unroll
  for (int i = 0; i < 4; i++) {
    const int m = m0 + ty * 4 + i;
    *(float4*)&out[(size_t)m * DIMM + n0 + tx * 4] =
        make_float4(acc[i][0] + bv.x, acc[i][1] + bv.y, acc[i][2] + bv.z, acc[i][3] + bv.w);
  }
}

// ---------------- launch ----------------
extern "C" void kernel_launch(void* const* d_in, const int* in_sizes, int n_in,
                              void* d_out, int out_size, void* d_ws, size_t ws_size,
                              hipStream_t stream) {
  (void)in_sizes; (void)n_in; (void)out_size; (void)ws_size;
  const float* x    = (const float*)d_in[0];
  const float* Wq   = (const float*)d_in[1];
  const float* Wk   = (const float*)d_in[2];
  const float* Wv   = (const float*)d_in[3];
  const float* Wrel = (const float*)d_in[4];
  const float* Wout = (const float*)d_in[5];
  const float* bout = (const float*)d_in[6];
  const float* cb   = (const float*)d_in[7];
  const float* pb   = (const float*)d_in[8];
  float* out = (float*)d_out;

  char* ws = (char*)d_ws;
  float* emb = (float*)(ws + OB_EMB);
  bf16* relk = (bf16*)(ws + OB_RELK);
  bf16* qc   = (bf16*)(ws + OB_QC);
  bf16* qp   = (bf16*)(ws + OB_QP);
  bf16* kk   = (bf16*)(ws + OB_K);
  bf16* vv   = (bf16*)(ws + OB_V);
  bf16* oh   = (bf16*)(ws + OB_OH);

  hipLaunchKernelGGL(pos_emb_kernel, dim3(2048), dim3(64), 0, stream, emb);
  hipLaunchKernelGGL(relk_kernel, dim3(4, NPOS), dim3(128), 0, stream, emb, Wrel, relk);
  hipLaunchKernelGGL((proj_gemm<0>), dim3(8, 64), dim3(256), 0, stream, x, Wq, cb, pb, qc, qp);
  hipLaunchKernelGGL((proj_gemm<1>), dim3(8, 64), dim3(256), 0, stream, x, Wk, cb, pb, kk, (bf16*)nullptr);
  hipLaunchKernelGGL((proj_gemm<2>), dim3(8, 64), dim3(256), 0, stream, x, Wv, cb, pb, vv, (bf16*)nullptr);
  hipLaunchKernelGGL(attn_mfma, dim3(SEQ / 64, BH), dim3(256), 0, stream,
                     (const short*)qc, (const short*)qp, (const short*)kk, (const short*)vv,
                     (const short*)relk, oh);
  hipLaunchKernelGGL(out_gemm, dim3(DIMM / 64, ROWS / 64), dim3(256), 0, stream, oh, Wout, bout, out);
}

// Round 5
// 434.332 us; speedup vs baseline: 2.8888x; 1.0552x over previous
//
#include <hip/hip_runtime.h>
#include <hip/hip_bf16.h>
#include <math.h>

typedef __hip_bfloat16 bf16;
typedef __attribute__((ext_vector_type(8))) short short8;  // 8 bf16 = 4 VGPRs
typedef __attribute__((ext_vector_type(4))) float f32x4;

#define SEQ   2048
#define NPOS  4095          // 2*SEQ-1
#define DIMM  768
#define HEADS 8
#define DK    64
#define HD    512           // HEADS*DK
#define BATCH 2
#define BH    16            // BATCH*HEADS
#define ROWS  4096          // BATCH*SEQ

// ---------------- workspace layout (BYTE offsets), ~44.4 MB ----------------
#define OB_RELK  ((size_t)0)                      // bf16 [8][4095][64] (+pad)
#define OB_QC    ((size_t)4194304)
#define OB_QP    ((size_t)8388608)
#define OB_K     ((size_t)12582912)
#define OB_V     ((size_t)16777216)
#define OB_OH    ((size_t)20971520)               // bf16 [4096][512]
// emb hi/lo alias the OH region (disjoint lifetimes: emb dies before attn runs)
#define OB_EMBH  OB_OH                            // bf16 [4096][192] (row 4095 zeroed)
#define OB_EMBL  ((size_t)(OB_OH + 1572864))
#define OB_XH    ((size_t)25165824)               // bf16 [4096][768]
#define OB_XL    ((size_t)31457280)
#define OB_WQKVH ((size_t)37748736)               // bf16 [1536][768]  (Wq|Wk|Wv transposed)
#define OB_WQKVL ((size_t)40108032)
#define OB_WOH   ((size_t)42467328)               // bf16 [768][512]   (Wout transposed)
#define OB_WOL   ((size_t)43253760)
#define OB_WRH   ((size_t)44040192)               // bf16 [512][192]   (Wrel transposed)
#define OB_WRL   ((size_t)44236800)

// RNE float -> bf16 bits (finite inputs only)
__device__ __forceinline__ unsigned f2bf(float f) {
  unsigned u = __float_as_uint(f);
  return (u + 0x7fffu + ((u >> 16) & 1u)) >> 16;
}
__device__ __forceinline__ void split2(float v, unsigned& hb, unsigned& lb) {
  hb = f2bf(v);
  const float back = __uint_as_float(hb << 16);
  lb = f2bf(v - back);
}

// ---------------- 1. positional embedding -> split bf16 ----------------
// one 32-lane group per row; lane j = basis j (nb=32). Row 4095 zero pad.
__global__ void pos_emb_kernel(short* __restrict__ eh, short* __restrict__ el) {
  const int row = blockIdx.x * 2 + (threadIdx.x >> 5);
  const int j   = threadIdx.x & 31;
  if (row >= NPOS) {           // row 4095 pad: zero so relk GEMM A-frag is clean
    for (int c = j; c < 192; c += 32) { eh[(size_t)row * 192 + c] = 0; el[(size_t)row * 192 + c] = 0; }
    return;
  }
  const float dist = (float)(row - (SEQ - 1));
  const float ad   = fabsf(dist);

  const float hl    = exp2f(3.0f + 8.0f * (float)j / 31.0f);
  const float f_exp = exp2f(-ad / hl);

  const float width = exp2f((float)(j + 1)) - 1.0f;
  const float f_cm  = (width > ad) ? 1.0f : 0.0f;

  float prob;
  if (ad > 0.0f) {
    const float c   = 4.0f * (float)((j + 1) * (j + 1));
    const float r   = (float)(j + 1) / 16.0f;
    const float lu  = (c - 1.0f) * logf(ad) - r * ad;
    const float ln_ = lgammaf(c) - c * logf(r);
    prob = expf(lu - ln_) + 1e-8f;
  } else {
    prob = 1e-8f;
  }
  float mx = prob;
  for (int off = 16; off; off >>= 1) mx = fmaxf(mx, __shfl_xor(mx, off, 32));
  const float f_g = prob / mx;

  const float s = (dist > 0.f) ? 1.f : ((dist < 0.f) ? -1.f : 0.f);
  const float vals[6] = {f_exp, f_cm, f_g, s * f_exp, s * f_cm, s * f_g};
  short* ph = eh + (size_t)row * 192;
  short* pl = el + (size_t)row * 192;
#pragma unroll
  for (int q = 0; q < 6; q++) {
    unsigned hb, lb;
    split2(vals[q], hb, lb);
    ph[q * 32 + j] = (short)hb;
    pl[q * 32 + j] = (short)lb;
  }
}

// ---------------- 2a. x fp32 -> split bf16 ----------------
__global__ void conv_split(const float* __restrict__ src, short* __restrict__ dh,
                           short* __restrict__ dl, int n4) {
  const int i = blockIdx.x * 256 + threadIdx.x;
  if (i >= n4) return;
  const float4 v = ((const float4*)src)[i];
  unsigned h0, l0, h1, l1, h2, l2, h3, l3;
  split2(v.x, h0, l0); split2(v.y, h1, l1); split2(v.z, h2, l2); split2(v.w, h3, l3);
  *(uint2*)&dh[(size_t)i * 4] = make_uint2(h0 | (h1 << 16), h2 | (h3 << 16));
  *(uint2*)&dl[(size_t)i * 4] = make_uint2(l0 | (l1 << 16), l2 | (l3 << 16));
}

// ---------------- 2b. transpose fp32 [R][C] -> split bf16 [C][R] ----------------
// grid (C/32, R/32), block 256
__global__ void transpose_split(const float* __restrict__ src, short* __restrict__ dh,
                                short* __restrict__ dl, int R, int C) {
  __shared__ float tile[32][33];
  const int t = threadIdx.x;
  const int c0 = blockIdx.x * 32, r0 = blockIdx.y * 32;
  {
    const int lr = t >> 3, lc = (t & 7) * 4;
    const float4 v = *(const float4*)&src[(size_t)(r0 + lr) * C + c0 + lc];
    tile[lr][lc] = v.x; tile[lr][lc + 1] = v.y; tile[lr][lc + 2] = v.z; tile[lr][lc + 3] = v.w;
  }
  __syncthreads();
  const int nn = t >> 3, kb = (t & 7) * 4;
  unsigned hb[4], lb[4];
#pragma unroll
  for (int e = 0; e < 4; e++) split2(tile[kb + e][nn], hb[e], lb[e]);
  const size_t o = (size_t)(c0 + nn) * R + r0 + kb;
  *(uint2*)&dh[o] = make_uint2(hb[0] | (hb[1] << 16), hb[2] | (hb[3] << 16));
  *(uint2*)&dl[o] = make_uint2(lb[0] | (lb[1] << 16), lb[2] | (lb[3] << 16));
}

// ---------------- 3. relk = emb @ Wrel (split-bf16 MFMA) ----------------
// M=4096(4095 valid), K=192, N=512; grid (64, 4), block 256 (4 waves x 16 rows)
__global__ __launch_bounds__(256) void relk_gemm(
    const short* __restrict__ eh, const short* __restrict__ el,
    const short* __restrict__ wh, const short* __restrict__ wl,
    bf16* __restrict__ relk) {
  const int t = threadIdx.x, lane = t & 63, w = t >> 6;
  const int quad = lane >> 4, l15 = lane & 15;
  const int m0 = blockIdx.x * 64 + w * 16;
  const int n0 = blockIdx.y * 128;
  f32x4 acc[8];
#pragma unroll
  for (int nt = 0; nt < 8; nt++) acc[nt] = (f32x4){0.f, 0.f, 0.f, 0.f};
  const size_t arow = (size_t)(m0 + l15) * 192 + quad * 8;
  for (int k0 = 0; k0 < 192; k0 += 32) {
    const short8 ah = *(const short8*)&eh[arow + k0];
    const short8 al = *(const short8*)&el[arow + k0];
#pragma unroll
    for (int nt = 0; nt < 8; nt++) {
      const size_t bo = (size_t)(n0 + nt * 16 + l15) * 192 + k0 + quad * 8;
      const short8 bh_ = *(const short8*)&wh[bo];
      const short8 bl_ = *(const short8*)&wl[bo];
      acc[nt] = __builtin_amdgcn_mfma_f32_16x16x32_bf16(ah, bh_, acc[nt], 0, 0, 0);
      acc[nt] = __builtin_amdgcn_mfma_f32_16x16x32_bf16(ah, bl_, acc[nt], 0, 0, 0);
      acc[nt] = __builtin_amdgcn_mfma_f32_16x16x32_bf16(al, bh_, acc[nt], 0, 0, 0);
    }
  }
#pragma unroll
  for (int nt = 0; nt < 8; nt++) {
    const int n = n0 + nt * 16 + l15;
    const int h = n >> 6, d = n & 63;
#pragma unroll
    for (int g = 0; g < 4; g++) {
      const int p = m0 + quad * 4 + g;
      if (p < NPOS) relk[((size_t)h * NPOS + p) * DK + d] = __float2bfloat16(acc[nt][g]);
    }
  }
}

// ---------------- 4. fused QKV projection (split-bf16 MFMA) ----------------
// M=4096, K=768, N=1536 (q|k|v); grid (64, 12), block 256
__global__ __launch_bounds__(256) void qkv_gemm(
    const short* __restrict__ xh, const short* __restrict__ xl,
    const short* __restrict__ wth, const short* __restrict__ wtl,
    const float* __restrict__ cb, const float* __restrict__ pb,
    bf16* __restrict__ qc, bf16* __restrict__ qp,
    bf16* __restrict__ kk, bf16* __restrict__ vv) {
  const int t = threadIdx.x, lane = t & 63, w = t >> 6;
  const int quad = lane >> 4, l15 = lane & 15;
  const int m0 = blockIdx.x * 64 + w * 16;
  const int n0 = blockIdx.y * 128;
  f32x4 acc[8];
#pragma unroll
  for (int nt = 0; nt < 8; nt++) acc[nt] = (f32x4){0.f, 0.f, 0.f, 0.f};
  const size_t arow = (size_t)(m0 + l15) * DIMM + quad * 8;
  for (int k0 = 0; k0 < DIMM; k0 += 32) {
    const short8 ah = *(const short8*)&xh[arow + k0];
    const short8 al = *(const short8*)&xl[arow + k0];
#pragma unroll
    for (int nt = 0; nt < 8; nt++) {
      const size_t bo = (size_t)(n0 + nt * 16 + l15) * DIMM + k0 + quad * 8;
      const short8 bh_ = *(const short8*)&wth[bo];
      const short8 bl_ = *(const short8*)&wtl[bo];
      acc[nt] = __builtin_amdgcn_mfma_f32_16x16x32_bf16(ah, bh_, acc[nt], 0, 0, 0);
      acc[nt] = __builtin_amdgcn_mfma_f32_16x16x32_bf16(ah, bl_, acc[nt], 0, 0, 0);
      acc[nt] = __builtin_amdgcn_mfma_f32_16x16x32_bf16(al, bh_, acc[nt], 0, 0, 0);
    }
  }
  const int sel = n0 >> 9;   // 0=q, 1=k, 2=v (block-uniform: 128 | 512)
#pragma unroll
  for (int nt = 0; nt < 8; nt++) {
    const int n = n0 + nt * 16 + l15;
    const int hd_ = n & 511, h = hd_ >> 6, d = hd_ & 63;
#pragma unroll
    for (int g = 0; g < 4; g++) {
      const int m = m0 + quad * 4 + g;
      const int b = m >> 11, s = m & 2047;
      const size_t idx = (((size_t)(b * HEADS + h) * SEQ) + s) * DK + d;
      const float v = acc[nt][g];
      if (sel == 0) {
        const float sv = v * 0.125f;     // dk^-0.5
        qc[idx] = __float2bfloat16(sv + cb[h * DK + d]);
        qp[idx] = __float2bfloat16(sv + pb[h * DK + d]);
      } else if (sel == 1) {
        kk[idx] = __float2bfloat16(v);
      } else {
        vv[idx] = __float2bfloat16(v);
      }
    }
  }
}

// ---------------- 5. MFMA fused attention (unchanged from round 4) ----------------
__global__ __launch_bounds__(256, 2) void attn_mfma(
    const short* __restrict__ qc, const short* __restrict__ qp,
    const short* __restrict__ kg, const short* __restrict__ vg,
    const short* __restrict__ relk, bf16* __restrict__ oh) {
  __shared__ short Rel_lds[128][72];
  __shared__ short Vt[64][72];
  __shared__ short Pw[4][16][72];
  __shared__ float Rw[4][16][84];

  const int t    = threadIdx.x;
  const int lane = t & 63;
  const int w    = t >> 6;
  const int quad = lane >> 4;
  const int l15  = lane & 15;
  const int bh   = blockIdx.y;
  const int b    = bh >> 3, h = bh & 7;
  const int i0   = blockIdx.x * 64;

  short8 qcA[2], qpA[2];
  {
    const size_t qrow = ((size_t)bh * SEQ + i0 + w * 16 + l15) * DK + quad * 8;
    qcA[0] = *(const short8*)(qc + qrow);
    qcA[1] = *(const short8*)(qc + qrow + 32);
    qpA[0] = *(const short8*)(qp + qrow);
    qpA[1] = *(const short8*)(qp + qrow + 32);
  }

  f32x4 oacc[4];
#pragma unroll
  for (int dt = 0; dt < 4; dt++) oacc[dt] = (f32x4){0.f, 0.f, 0.f, 0.f};
  float m_i[4] = {-1e30f, -1e30f, -1e30f, -1e30f};
  float l_i[4] = {0.f, 0.f, 0.f, 0.f};

  const int vjj = t & 63, vdb = (t >> 6) * 16;
  const int rr  = t >> 1, rcc = (t & 1) * 32;
  const int rbase = 48 - 16 * w;

  for (int jt = 0; jt < SEQ / 64; jt++) {
    const int j0 = jt * 64;
    __syncthreads();
    {
      const short* src = vg + ((size_t)bh * SEQ + j0 + vjj) * DK + vdb;
      uint4 a = *(const uint4*)src;
      uint4 c = *(const uint4*)(src + 8);
      const short* pa = (const short*)&a;
      const short* pc = (const short*)&c;
#pragma unroll
      for (int e = 0; e < 8; e++) {
        Vt[vdb + e][vjj]     = pa[e];
        Vt[vdb + 8 + e][vjj] = pc[e];
      }
    }
    {
      const short* src = relk + ((size_t)h * NPOS + (j0 - i0 + 1984) + rr) * DK + rcc;
      *(uint4*)&Rel_lds[rr][rcc]      = *(const uint4*)(src);
      *(uint4*)&Rel_lds[rr][rcc + 8]  = *(const uint4*)(src + 8);
      *(uint4*)&Rel_lds[rr][rcc + 16] = *(const uint4*)(src + 16);
      *(uint4*)&Rel_lds[rr][rcc + 24] = *(const uint4*)(src + 24);
    }
    __syncthreads();

    f32x4 sacc[4];
#pragma unroll
    for (int nt = 0; nt < 4; nt++) {
      const short* kr = kg + ((size_t)bh * SEQ + j0 + nt * 16 + l15) * DK + quad * 8;
      short8 b0 = *(const short8*)kr;
      short8 b1 = *(const short8*)(kr + 32);
      f32x4 acc = (f32x4){0.f, 0.f, 0.f, 0.f};
      acc = __builtin_amdgcn_mfma_f32_16x16x32_bf16(qcA[0], b0, acc, 0, 0, 0);
      acc = __builtin_amdgcn_mfma_f32_16x16x32_bf16(qcA[1], b1, acc, 0, 0, 0);
      sacc[nt] = acc;
    }
#pragma unroll
    for (int ut = 0; ut < 5; ut++) {
      const short* rl = &Rel_lds[rbase + ut * 16 + l15][quad * 8];
      short8 b0 = *(const short8*)rl;
      short8 b1 = *(const short8*)(rl + 32);
      f32x4 acc = (f32x4){0.f, 0.f, 0.f, 0.f};
      acc = __builtin_amdgcn_mfma_f32_16x16x32_bf16(qpA[0], b0, acc, 0, 0, 0);
      acc = __builtin_amdgcn_mfma_f32_16x16x32_bf16(qpA[1], b1, acc, 0, 0, 0);
#pragma unroll
      for (int g = 0; g < 4; g++) Rw[w][quad * 4 + g][ut * 16 + l15] = acc[g];
    }
#pragma unroll
    for (int nt = 0; nt < 4; nt++) {
#pragma unroll
      for (int g = 0; g < 4; g++) {
        const int r = quad * 4 + g;
        sacc[nt][g] += Rw[w][r][nt * 16 + l15 - r + 15];
      }
    }

    float m_new[4], alpha[4], lrow[4];
#pragma unroll
    for (int g = 0; g < 4; g++) {
      float mm = fmaxf(fmaxf(sacc[0][g], sacc[1][g]), fmaxf(sacc[2][g], sacc[3][g]));
      mm = fmaxf(mm, __shfl_xor(mm, 1, 16));
      mm = fmaxf(mm, __shfl_xor(mm, 2, 16));
      mm = fmaxf(mm, __shfl_xor(mm, 4, 16));
      mm = fmaxf(mm, __shfl_xor(mm, 8, 16));
      m_new[g] = fmaxf(m_i[g], mm);
      alpha[g] = expf(m_i[g] - m_new[g]);
      m_i[g]   = m_new[g];
      lrow[g]  = 0.f;
    }
#pragma unroll
    for (int nt = 0; nt < 4; nt++) {
#pragma unroll
      for (int g = 0; g < 4; g++) {
        const float p = expf(sacc[nt][g] - m_new[g]);
        lrow[g] += p;
        Pw[w][quad * 4 + g][nt * 16 + l15] = (short)f2bf(p);
      }
    }
#pragma unroll
    for (int g = 0; g < 4; g++) {
      float ls = lrow[g];
      ls += __shfl_xor(ls, 1, 16);
      ls += __shfl_xor(ls, 2, 16);
      ls += __shfl_xor(ls, 4, 16);
      ls += __shfl_xor(ls, 8, 16);
      l_i[g] = l_i[g] * alpha[g] + ls;
    }
#pragma unroll
    for (int dt = 0; dt < 4; dt++) {
#pragma unroll
      for (int g = 0; g < 4; g++) oacc[dt][g] *= alpha[g];
    }

#pragma unroll
    for (int ks = 0; ks < 2; ks++) {
      short8 pA = *(const short8*)&Pw[w][l15][ks * 32 + quad * 8];
#pragma unroll
      for (int dt = 0; dt < 4; dt++) {
        short8 vB = *(const short8*)&Vt[dt * 16 + l15][ks * 32 + quad * 8];
        oacc[dt] = __builtin_amdgcn_mfma_f32_16x16x32_bf16(pA, vB, oacc[dt], 0, 0, 0);
      }
    }
  }

#pragma unroll
  for (int g = 0; g < 4; g++) {
    const float inv = 1.0f / l_i[g];
    const int irow = i0 + w * 16 + quad * 4 + g;
    bf16* dst = oh + ((size_t)(b * SEQ) + irow) * HD + h * DK + l15;
#pragma unroll
    for (int dt = 0; dt < 4; dt++)
      dst[dt * 16] = __float2bfloat16(oacc[dt][g] * inv);
  }
}

// ---------------- 6. output projection (bf16 A x split-bf16 W MFMA) ----------------
// M=4096, K=512, N=768; grid (64, 6), block 256
__global__ __launch_bounds__(256) void out_gemm_mfma(
    const short* __restrict__ ohp, const short* __restrict__ wh,
    const short* __restrict__ wl, const float* __restrict__ bias,
    float* __restrict__ out) {
  const int t = threadIdx.x, lane = t & 63, w = t >> 6;
  const int quad = lane >> 4, l15 = lane & 15;
  const int m0 = blockIdx.x * 64 + w * 16;
  const int n0 = blockIdx.y * 128;
  f32x4 acc[8];
#pragma unroll
  for (int nt = 0; nt < 8; nt++) acc[nt] = (f32x4){0.f, 0.f, 0.f, 0.f};
  const size_t arow = (size_t)(m0 + l15) * HD + quad * 8;
  for (int k0 = 0; k0 < HD; k0 += 32) {
    const short8 a = *(const short8*)&ohp[arow + k0];
#pragma unroll
    for (int nt = 0; nt < 8; nt++) {
      const size_t bo = (size_t)(n0 + nt * 16 + l15) * HD + k0 + quad * 8;
      const short8 bh_ = *(const short8*)&wh[bo];
      const short8 bl_ = *(const short8*)&wl[bo];
      acc[nt] = __builtin_amdgcn_mfma_f32_16x16x32_bf16(a, bh_, acc[nt], 0, 0, 0);
      acc[nt] = __builtin_amdgcn_mfma_f32_16x16x32_bf16(a, bl_, acc[nt], 0, 0, 0);
    }
  }
#pragma unroll
  for (int nt = 0; nt < 8; nt++) {
    const int n = n0 + nt * 16 + l15;
    const float bv = bias[n];
#pragma unroll
    for (int g = 0; g < 4; g++) {
      const int m = m0 + quad * 4 + g;
      out[(size_t)m * DIMM + n] = acc[nt][g] + bv;
    }
  }
}

// ---------------- launch ----------------
extern "C" void kernel_launch(void* const* d_in, const int* in_sizes, int n_in,
                              void* d_out, int out_size, void* d_ws, size_t ws_size,
                              hipStream_t stream) {
  (void)in_sizes; (void)n_in; (void)out_size; (void)ws_size;
  const float* x    = (const float*)d_in[0];
  const float* Wq   = (const float*)d_in[1];
  const float* Wk   = (const float*)d_in[2];
  const float* Wv   = (const float*)d_in[3];
  const float* Wrel = (const float*)d_in[4];
  const float* Wout = (const float*)d_in[5];
  const float* bout = (const float*)d_in[6];
  const float* cb   = (const float*)d_in[7];
  const float* pb   = (const float*)d_in[8];
  float* out = (float*)d_out;

  char* ws = (char*)d_ws;
  bf16*  relk = (bf16*)(ws + OB_RELK);
  bf16*  qc   = (bf16*)(ws + OB_QC);
  bf16*  qp   = (bf16*)(ws + OB_QP);
  bf16*  kk   = (bf16*)(ws + OB_K);
  bf16*  vv   = (bf16*)(ws + OB_V);
  bf16*  oh   = (bf16*)(ws + OB_OH);
  short* embh = (short*)(ws + OB_EMBH);
  short* embl = (short*)(ws + OB_EMBL);
  short* xh   = (short*)(ws + OB_XH);
  short* xl   = (short*)(ws + OB_XL);
  short* wqh  = (short*)(ws + OB_WQKVH);
  short* wql  = (short*)(ws + OB_WQKVL);
  short* woh  = (short*)(ws + OB_WOH);
  short* wol  = (short*)(ws + OB_WOL);
  short* wrh  = (short*)(ws + OB_WRH);
  short* wrl  = (short*)(ws + OB_WRL);

  // prep: features + fp32->split-bf16 conversions/transposes
  hipLaunchKernelGGL(pos_emb_kernel, dim3(2048), dim3(64), 0, stream, embh, embl);
  hipLaunchKernelGGL(conv_split, dim3(3072), dim3(256), 0, stream, x, xh, xl, ROWS * DIMM / 4);
  hipLaunchKernelGGL(transpose_split, dim3(16, 24), dim3(256), 0, stream, Wq,   wqh,                wql,                DIMM, HD);
  hipLaunchKernelGGL(transpose_split, dim3(16, 24), dim3(256), 0, stream, Wk,   wqh + 512 * DIMM,   wql + 512 * DIMM,   DIMM, HD);
  hipLaunchKernelGGL(transpose_split, dim3(16, 24), dim3(256), 0, stream, Wv,   wqh + 1024 * DIMM,  wql + 1024 * DIMM,  DIMM, HD);
  hipLaunchKernelGGL(transpose_split, dim3(24, 16), dim3(256), 0, stream, Wout, woh,                wol,                HD,   DIMM);
  hipLaunchKernelGGL(transpose_split, dim3(16, 6),  dim3(256), 0, stream, Wrel, wrh,                wrl,                192,  HD);

  // GEMMs + attention
  hipLaunchKernelGGL(relk_gemm, dim3(64, 4), dim3(256), 0, stream, embh, embl, wrh, wrl, relk);
  hipLaunchKernelGGL(qkv_gemm, dim3(64, 12), dim3(256), 0, stream, xh, xl, wqh, wql, cb, pb, qc, qp, kk, vv);
  hipLaunchKernelGGL(attn_mfma, dim3(SEQ / 64, BH), dim3(256), 0, stream,
                     (const short*)qc, (const short*)qp, (const short*)kk, (const short*)vv,
                     (const short*)relk, oh);
  hipLaunchKernelGGL(out_gemm_mfma, dim3(64, 6), dim3(256), 0, stream,
                     (const short*)oh, woh, wol, bout, out);
}

// Round 6
// 284.875 us; speedup vs baseline: 4.4044x; 1.5246x over previous
//
#include <hip/hip_runtime.h>
#include <hip/hip_bf16.h>
#include <math.h>

typedef __hip_bfloat16 bf16;
typedef __attribute__((ext_vector_type(8))) short short8;  // 8 bf16 = 4 VGPRs
typedef __attribute__((ext_vector_type(4))) float f32x4;

#define SEQ   2048
#define NPOS  4095          // 2*SEQ-1
#define DIMM  768
#define HEADS 8
#define DK    64
#define HD    512           // HEADS*DK
#define BATCH 2
#define BH    16            // BATCH*HEADS
#define ROWS  4096          // BATCH*SEQ

// ---------------- workspace layout (BYTE offsets), ~44.4 MB ----------------
#define OB_RELK  ((size_t)0)                      // bf16 [8][4095][64] (+pad)
#define OB_QC    ((size_t)4194304)
#define OB_QP    ((size_t)8388608)
#define OB_K     ((size_t)12582912)
#define OB_V     ((size_t)16777216)
#define OB_OH    ((size_t)20971520)               // bf16 [4096][512]
// emb hi/lo alias the OH region (disjoint lifetimes: emb dies before attn runs)
#define OB_EMBH  OB_OH                            // bf16 [4096][192] (row 4095 zeroed)
#define OB_EMBL  ((size_t)(OB_OH + 1572864))
#define OB_XH    ((size_t)25165824)               // bf16 [4096][768]
#define OB_XL    ((size_t)31457280)
#define OB_WQKVH ((size_t)37748736)               // bf16 [1536][768]  (Wq|Wk|Wv transposed)
#define OB_WQKVL ((size_t)40108032)
#define OB_WOH   ((size_t)42467328)               // bf16 [768][512]   (Wout transposed)
#define OB_WOL   ((size_t)43253760)
#define OB_WRH   ((size_t)44040192)               // bf16 [512][192]   (Wrel transposed)
#define OB_WRL   ((size_t)44236800)

// RNE float -> bf16 bits (finite inputs only)
__device__ __forceinline__ unsigned f2bf(float f) {
  unsigned u = __float_as_uint(f);
  return (u + 0x7fffu + ((u >> 16) & 1u)) >> 16;
}
__device__ __forceinline__ void split2(float v, unsigned& hb, unsigned& lb) {
  hb = f2bf(v);
  const float back = __uint_as_float(hb << 16);
  lb = f2bf(v - back);
}

// ---------------- 1. positional embedding -> split bf16 ----------------
__global__ void pos_emb_kernel(short* __restrict__ eh, short* __restrict__ el) {
  const int row = blockIdx.x * 2 + (threadIdx.x >> 5);
  const int j   = threadIdx.x & 31;
  if (row >= NPOS) {           // row 4095 pad: zero so relk GEMM A-frag is clean
    for (int c = j; c < 192; c += 32) { eh[(size_t)row * 192 + c] = 0; el[(size_t)row * 192 + c] = 0; }
    return;
  }
  const float dist = (float)(row - (SEQ - 1));
  const float ad   = fabsf(dist);

  const float hl    = exp2f(3.0f + 8.0f * (float)j / 31.0f);
  const float f_exp = exp2f(-ad / hl);

  const float width = exp2f((float)(j + 1)) - 1.0f;
  const float f_cm  = (width > ad) ? 1.0f : 0.0f;

  float prob;
  if (ad > 0.0f) {
    const float c   = 4.0f * (float)((j + 1) * (j + 1));
    const float r   = (float)(j + 1) / 16.0f;
    const float lu  = (c - 1.0f) * logf(ad) - r * ad;
    const float ln_ = lgammaf(c) - c * logf(r);
    prob = expf(lu - ln_) + 1e-8f;
  } else {
    prob = 1e-8f;
  }
  float mx = prob;
  for (int off = 16; off; off >>= 1) mx = fmaxf(mx, __shfl_xor(mx, off, 32));
  const float f_g = prob / mx;

  const float s = (dist > 0.f) ? 1.f : ((dist < 0.f) ? -1.f : 0.f);
  const float vals[6] = {f_exp, f_cm, f_g, s * f_exp, s * f_cm, s * f_g};
  short* ph = eh + (size_t)row * 192;
  short* pl = el + (size_t)row * 192;
#pragma unroll
  for (int q = 0; q < 6; q++) {
    unsigned hb, lb;
    split2(vals[q], hb, lb);
    ph[q * 32 + j] = (short)hb;
    pl[q * 32 + j] = (short)lb;
  }
}

// ---------------- 2a. x fp32 -> split bf16 ----------------
__global__ void conv_split(const float* __restrict__ src, short* __restrict__ dh,
                           short* __restrict__ dl, int n4) {
  const int i = blockIdx.x * 256 + threadIdx.x;
  if (i >= n4) return;
  const float4 v = ((const float4*)src)[i];
  unsigned h0, l0, h1, l1, h2, l2, h3, l3;
  split2(v.x, h0, l0); split2(v.y, h1, l1); split2(v.z, h2, l2); split2(v.w, h3, l3);
  *(uint2*)&dh[(size_t)i * 4] = make_uint2(h0 | (h1 << 16), h2 | (h3 << 16));
  *(uint2*)&dl[(size_t)i * 4] = make_uint2(l0 | (l1 << 16), l2 | (l3 << 16));
}

// ---------------- 2b. transpose fp32 [R][C] -> split bf16 [C][R] ----------------
__global__ void transpose_split(const float* __restrict__ src, short* __restrict__ dh,
                                short* __restrict__ dl, int R, int C) {
  __shared__ float tile[32][33];
  const int t = threadIdx.x;
  const int c0 = blockIdx.x * 32, r0 = blockIdx.y * 32;
  {
    const int lr = t >> 3, lc = (t & 7) * 4;
    const float4 v = *(const float4*)&src[(size_t)(r0 + lr) * C + c0 + lc];
    tile[lr][lc] = v.x; tile[lr][lc + 1] = v.y; tile[lr][lc + 2] = v.z; tile[lr][lc + 3] = v.w;
  }
  __syncthreads();
  const int nn = t >> 3, kb = (t & 7) * 4;
  unsigned hb[4], lb[4];
#pragma unroll
  for (int e = 0; e < 4; e++) split2(tile[kb + e][nn], hb[e], lb[e]);
  const size_t o = (size_t)(c0 + nn) * R + r0 + kb;
  *(uint2*)&dh[o] = make_uint2(hb[0] | (hb[1] << 16), hb[2] | (hb[3] << 16));
  *(uint2*)&dl[o] = make_uint2(lb[0] | (lb[1] << 16), lb[2] | (lb[3] << 16));
}

// ---------------- 3. tiled split-bf16 MFMA GEMM, 128x128 tile, BK=32 ----------------
// A [M][K] (hi/lo), B pre-transposed [N][K] (hi/lo). 256 thr = 2x2 waves,
// wave quadrant 64x64 = 4x4 MFMA tiles. LDS rows padded to 40 shorts
// (16B-aligned b128, <=2-way banks). EPI: 0=qkv scatter, 1=relk, 2=out+bias.
template <int EPI, int SPLITA, int KDIM>
__global__ __launch_bounds__(256) void gemm128(
    const short* __restrict__ Ah, const short* __restrict__ Al,
    const short* __restrict__ Bhp, const short* __restrict__ Blp,
    const float* __restrict__ cb, const float* __restrict__ pb,
    const float* __restrict__ bias,
    bf16* __restrict__ oq, bf16* __restrict__ oqp,
    bf16* __restrict__ ok, bf16* __restrict__ ov,
    float* __restrict__ ofp) {
  __shared__ short AsH[128][40];
  __shared__ short AsL[SPLITA ? 128 : 1][40];
  __shared__ short BsH[128][40];
  __shared__ short BsL[128][40];

  const int t = threadIdx.x, lane = t & 63, w = t >> 6;
  const int quad = lane >> 4, l15 = lane & 15;
  const int wm = (w >> 1) * 64, wn = (w & 1) * 64;
  const int m0 = blockIdx.x * 128, n0 = blockIdx.y * 128;

  const int sr = t >> 1;            // staging row 0..127
  const int sc = (t & 1) * 16;      // staging col (shorts)

  f32x4 acc[4][4];
#pragma unroll
  for (int i = 0; i < 4; i++)
#pragma unroll
    for (int j = 0; j < 4; j++) acc[i][j] = (f32x4){0.f, 0.f, 0.f, 0.f};

  for (int k0 = 0; k0 < KDIM; k0 += 32) {
    __syncthreads();
    {
      const size_t ga = (size_t)(m0 + sr) * KDIM + k0 + sc;
      *(uint4*)&AsH[sr][sc]     = *(const uint4*)&Ah[ga];
      *(uint4*)&AsH[sr][sc + 8] = *(const uint4*)&Ah[ga + 8];
      if (SPLITA) {
        *(uint4*)&AsL[sr][sc]     = *(const uint4*)&Al[ga];
        *(uint4*)&AsL[sr][sc + 8] = *(const uint4*)&Al[ga + 8];
      }
      const size_t gb = (size_t)(n0 + sr) * KDIM + k0 + sc;
      *(uint4*)&BsH[sr][sc]     = *(const uint4*)&Bhp[gb];
      *(uint4*)&BsH[sr][sc + 8] = *(const uint4*)&Bhp[gb + 8];
      *(uint4*)&BsL[sr][sc]     = *(const uint4*)&Blp[gb];
      *(uint4*)&BsL[sr][sc + 8] = *(const uint4*)&Blp[gb + 8];
    }
    __syncthreads();

    short8 amh[4], aml[4], bnh[4], bnl[4];
#pragma unroll
    for (int i = 0; i < 4; i++) {
      amh[i] = *(const short8*)&AsH[wm + i * 16 + l15][quad * 8];
      if (SPLITA) aml[i] = *(const short8*)&AsL[wm + i * 16 + l15][quad * 8];
      bnh[i] = *(const short8*)&BsH[wn + i * 16 + l15][quad * 8];
      bnl[i] = *(const short8*)&BsL[wn + i * 16 + l15][quad * 8];
    }
#pragma unroll
    for (int i = 0; i < 4; i++) {
#pragma unroll
      for (int j = 0; j < 4; j++) {
        acc[i][j] = __builtin_amdgcn_mfma_f32_16x16x32_bf16(amh[i], bnh[j], acc[i][j], 0, 0, 0);
        acc[i][j] = __builtin_amdgcn_mfma_f32_16x16x32_bf16(amh[i], bnl[j], acc[i][j], 0, 0, 0);
        if (SPLITA)
          acc[i][j] = __builtin_amdgcn_mfma_f32_16x16x32_bf16(aml[i], bnh[j], acc[i][j], 0, 0, 0);
      }
    }
  }

  const int sel = (EPI == 0) ? (int)(blockIdx.y >> 2) : 0;   // 0=q,1=k,2=v
#pragma unroll
  for (int i = 0; i < 4; i++) {
#pragma unroll
    for (int j = 0; j < 4; j++) {
      const int n = n0 + wn + j * 16 + l15;
#pragma unroll
      for (int g = 0; g < 4; g++) {
        const int m = m0 + wm + i * 16 + quad * 4 + g;
        const float v = acc[i][j][g];
        if (EPI == 0) {
          const int hd_ = n & 511, hh = hd_ >> 6, d = hd_ & 63;
          const int b = m >> 11, s = m & 2047;
          const size_t idx = (((size_t)(b * HEADS + hh) * SEQ) + s) * DK + d;
          if (sel == 0) {
            const float sv = v * 0.125f;   // dk^-0.5
            oq[idx]  = __float2bfloat16(sv + cb[hh * DK + d]);
            oqp[idx] = __float2bfloat16(sv + pb[hh * DK + d]);
          } else if (sel == 1) {
            ok[idx] = __float2bfloat16(v);
          } else {
            ov[idx] = __float2bfloat16(v);
          }
        } else if (EPI == 1) {
          const int hh = n >> 6, d = n & 63;
          if (m < NPOS) oq[((size_t)hh * NPOS + m) * DK + d] = __float2bfloat16(v);
        } else {
          ofp[(size_t)m * DIMM + n] = v + bias[n];
        }
      }
    }
  }
}

// ---------------- 4. MFMA fused attention (unchanged from round 4) ----------------
__global__ __launch_bounds__(256, 2) void attn_mfma(
    const short* __restrict__ qc, const short* __restrict__ qp,
    const short* __restrict__ kg, const short* __restrict__ vg,
    const short* __restrict__ relk, bf16* __restrict__ oh) {
  __shared__ short Rel_lds[128][72];
  __shared__ short Vt[64][72];
  __shared__ short Pw[4][16][72];
  __shared__ float Rw[4][16][84];

  const int t    = threadIdx.x;
  const int lane = t & 63;
  const int w    = t >> 6;
  const int quad = lane >> 4;
  const int l15  = lane & 15;
  const int bh   = blockIdx.y;
  const int b    = bh >> 3, h = bh & 7;
  const int i0   = blockIdx.x * 64;

  short8 qcA[2], qpA[2];
  {
    const size_t qrow = ((size_t)bh * SEQ + i0 + w * 16 + l15) * DK + quad * 8;
    qcA[0] = *(const short8*)(qc + qrow);
    qcA[1] = *(const short8*)(qc + qrow + 32);
    qpA[0] = *(const short8*)(qp + qrow);
    qpA[1] = *(const short8*)(qp + qrow + 32);
  }

  f32x4 oacc[4];
#pragma unroll
  for (int dt = 0; dt < 4; dt++) oacc[dt] = (f32x4){0.f, 0.f, 0.f, 0.f};
  float m_i[4] = {-1e30f, -1e30f, -1e30f, -1e30f};
  float l_i[4] = {0.f, 0.f, 0.f, 0.f};

  const int vjj = t & 63, vdb = (t >> 6) * 16;
  const int rr  = t >> 1, rcc = (t & 1) * 32;
  const int rbase = 48 - 16 * w;

  for (int jt = 0; jt < SEQ / 64; jt++) {
    const int j0 = jt * 64;
    __syncthreads();
    {
      const short* src = vg + ((size_t)bh * SEQ + j0 + vjj) * DK + vdb;
      uint4 a = *(const uint4*)src;
      uint4 c = *(const uint4*)(src + 8);
      const short* pa = (const short*)&a;
      const short* pc = (const short*)&c;
#pragma unroll
      for (int e = 0; e < 8; e++) {
        Vt[vdb + e][vjj]     = pa[e];
        Vt[vdb + 8 + e][vjj] = pc[e];
      }
    }
    {
      const short* src = relk + ((size_t)h * NPOS + (j0 - i0 + 1984) + rr) * DK + rcc;
      *(uint4*)&Rel_lds[rr][rcc]      = *(const uint4*)(src);
      *(uint4*)&Rel_lds[rr][rcc + 8]  = *(const uint4*)(src + 8);
      *(uint4*)&Rel_lds[rr][rcc + 16] = *(const uint4*)(src + 16);
      *(uint4*)&Rel_lds[rr][rcc + 24] = *(const uint4*)(src + 24);
    }
    __syncthreads();

    f32x4 sacc[4];
#pragma unroll
    for (int nt = 0; nt < 4; nt++) {
      const short* kr = kg + ((size_t)bh * SEQ + j0 + nt * 16 + l15) * DK + quad * 8;
      short8 b0 = *(const short8*)kr;
      short8 b1 = *(const short8*)(kr + 32);
      f32x4 acc = (f32x4){0.f, 0.f, 0.f, 0.f};
      acc = __builtin_amdgcn_mfma_f32_16x16x32_bf16(qcA[0], b0, acc, 0, 0, 0);
      acc = __builtin_amdgcn_mfma_f32_16x16x32_bf16(qcA[1], b1, acc, 0, 0, 0);
      sacc[nt] = acc;
    }
#pragma unroll
    for (int ut = 0; ut < 5; ut++) {
      const short* rl = &Rel_lds[rbase + ut * 16 + l15][quad * 8];
      short8 b0 = *(const short8*)rl;
      short8 b1 = *(const short8*)(rl + 32);
      f32x4 acc = (f32x4){0.f, 0.f, 0.f, 0.f};
      acc = __builtin_amdgcn_mfma_f32_16x16x32_bf16(qpA[0], b0, acc, 0, 0, 0);
      acc = __builtin_amdgcn_mfma_f32_16x16x32_bf16(qpA[1], b1, acc, 0, 0, 0);
#pragma unroll
      for (int g = 0; g < 4; g++) Rw[w][quad * 4 + g][ut * 16 + l15] = acc[g];
    }
#pragma unroll
    for (int nt = 0; nt < 4; nt++) {
#pragma unroll
      for (int g = 0; g < 4; g++) {
        const int r = quad * 4 + g;
        sacc[nt][g] += Rw[w][r][nt * 16 + l15 - r + 15];
      }
    }

    float m_new[4], alpha[4], lrow[4];
#pragma unroll
    for (int g = 0; g < 4; g++) {
      float mm = fmaxf(fmaxf(sacc[0][g], sacc[1][g]), fmaxf(sacc[2][g], sacc[3][g]));
      mm = fmaxf(mm, __shfl_xor(mm, 1, 16));
      mm = fmaxf(mm, __shfl_xor(mm, 2, 16));
      mm = fmaxf(mm, __shfl_xor(mm, 4, 16));
      mm = fmaxf(mm, __shfl_xor(mm, 8, 16));
      m_new[g] = fmaxf(m_i[g], mm);
      alpha[g] = expf(m_i[g] - m_new[g]);
      m_i[g]   = m_new[g];
      lrow[g]  = 0.f;
    }
#pragma unroll
    for (int nt = 0; nt < 4; nt++) {
#pragma unroll
      for (int g = 0; g < 4; g++) {
        const float p = expf(sacc[nt][g] - m_new[g]);
        lrow[g] += p;
        Pw[w][quad * 4 + g][nt * 16 + l15] = (short)f2bf(p);
      }
    }
#pragma unroll
    for (int g = 0; g < 4; g++) {
      float ls = lrow[g];
      ls += __shfl_xor(ls, 1, 16);
      ls += __shfl_xor(ls, 2, 16);
      ls += __shfl_xor(ls, 4, 16);
      ls += __shfl_xor(ls, 8, 16);
      l_i[g] = l_i[g] * alpha[g] + ls;
    }
#pragma unroll
    for (int dt = 0; dt < 4; dt++) {
#pragma unroll
      for (int g = 0; g < 4; g++) oacc[dt][g] *= alpha[g];
    }

#pragma unroll
    for (int ks = 0; ks < 2; ks++) {
      short8 pA = *(const short8*)&Pw[w][l15][ks * 32 + quad * 8];
#pragma unroll
      for (int dt = 0; dt < 4; dt++) {
        short8 vB = *(const short8*)&Vt[dt * 16 + l15][ks * 32 + quad * 8];
        oacc[dt] = __builtin_amdgcn_mfma_f32_16x16x32_bf16(pA, vB, oacc[dt], 0, 0, 0);
      }
    }
  }

#pragma unroll
  for (int g = 0; g < 4; g++) {
    const float inv = 1.0f / l_i[g];
    const int irow = i0 + w * 16 + quad * 4 + g;
    bf16* dst = oh + ((size_t)(b * SEQ) + irow) * HD + h * DK + l15;
#pragma unroll
    for (int dt = 0; dt < 4; dt++)
      dst[dt * 16] = __float2bfloat16(oacc[dt][g] * inv);
  }
}

// ---------------- launch ----------------
extern "C" void kernel_launch(void* const* d_in, const int* in_sizes, int n_in,
                              void* d_out, int out_size, void* d_ws, size_t ws_size,
                              hipStream_t stream) {
  (void)in_sizes; (void)n_in; (void)out_size; (void)ws_size;
  const float* x    = (const float*)d_in[0];
  const float* Wq   = (const float*)d_in[1];
  const float* Wk   = (const float*)d_in[2];
  const float* Wv   = (const float*)d_in[3];
  const float* Wrel = (const float*)d_in[4];
  const float* Wout = (const float*)d_in[5];
  const float* bout = (const float*)d_in[6];
  const float* cb   = (const float*)d_in[7];
  const float* pb   = (const float*)d_in[8];
  float* out = (float*)d_out;

  char* ws = (char*)d_ws;
  bf16*  relk = (bf16*)(ws + OB_RELK);
  bf16*  qc   = (bf16*)(ws + OB_QC);
  bf16*  qp   = (bf16*)(ws + OB_QP);
  bf16*  kk   = (bf16*)(ws + OB_K);
  bf16*  vv   = (bf16*)(ws + OB_V);
  bf16*  oh   = (bf16*)(ws + OB_OH);
  short* embh = (short*)(ws + OB_EMBH);
  short* embl = (short*)(ws + OB_EMBL);
  short* xh   = (short*)(ws + OB_XH);
  short* xl   = (short*)(ws + OB_XL);
  short* wqh  = (short*)(ws + OB_WQKVH);
  short* wql  = (short*)(ws + OB_WQKVL);
  short* woh  = (short*)(ws + OB_WOH);
  short* wol  = (short*)(ws + OB_WOL);
  short* wrh  = (short*)(ws + OB_WRH);
  short* wrl  = (short*)(ws + OB_WRL);

  // prep: features + fp32->split-bf16 conversions/transposes
  hipLaunchKernelGGL(pos_emb_kernel, dim3(2048), dim3(64), 0, stream, embh, embl);
  hipLaunchKernelGGL(conv_split, dim3(3072), dim3(256), 0, stream, x, xh, xl, ROWS * DIMM / 4);
  hipLaunchKernelGGL(transpose_split, dim3(16, 24), dim3(256), 0, stream, Wq,   wqh,                wql,                DIMM, HD);
  hipLaunchKernelGGL(transpose_split, dim3(16, 24), dim3(256), 0, stream, Wk,   wqh + 512 * DIMM,   wql + 512 * DIMM,   DIMM, HD);
  hipLaunchKernelGGL(transpose_split, dim3(16, 24), dim3(256), 0, stream, Wv,   wqh + 1024 * DIMM,  wql + 1024 * DIMM,  DIMM, HD);
  hipLaunchKernelGGL(transpose_split, dim3(24, 16), dim3(256), 0, stream, Wout, woh,                wol,                HD,   DIMM);
  hipLaunchKernelGGL(transpose_split, dim3(16, 6),  dim3(256), 0, stream, Wrel, wrh,                wrl,                192,  HD);

  // GEMMs + attention (LDS-tiled MFMA)
  hipLaunchKernelGGL((gemm128<1, 1, 192>), dim3(32, 4), dim3(256), 0, stream,
                     embh, embl, wrh, wrl, nullptr, nullptr, nullptr,
                     relk, nullptr, nullptr, nullptr, nullptr);
  hipLaunchKernelGGL((gemm128<0, 1, DIMM>), dim3(32, 12), dim3(256), 0, stream,
                     xh, xl, wqh, wql, cb, pb, nullptr,
                     qc, qp, kk, vv, nullptr);
  hipLaunchKernelGGL(attn_mfma, dim3(SEQ / 64, BH), dim3(256), 0, stream,
                     (const short*)qc, (const short*)qp, (const short*)kk, (const short*)vv,
                     (const short*)relk, oh);
  hipLaunchKernelGGL((gemm128<2, 0, HD>), dim3(32, 6), dim3(256), 0, stream,
                     (const short*)oh, nullptr, woh, wol, nullptr, nullptr, bout,
                     nullptr, nullptr, nullptr, nullptr, out);
}